// Round 1
// baseline (10320.594 us; speedup 1.0000x reference)
//
#include <hip/hip_runtime.h>
#include <hip/hip_bf16.h>

// RNN scratch: inputs [T=512,B=256,I=1024] fp32, W_xh [1024,1024], W_hh [1024,1024], b_h [1024]
// out = outputs [T,B,H] fp32 ++ final_state [B,H] fp32
//
// Phase 1: xw = X @ W_xh + b_h  (bf16 MFMA, 128x128 tile), written into d_out outputs region.
// Phase 2: persistent kernel, 16 teams x 16 wgs; team owns 16 batch rows, wg owns 64 H cols
//          with W_hh^T slice (1024x64 bf16, padded) resident in LDS. Per-step per-team
//          atomic barrier; double-buffered global bf16 state.

#define T_STEPS 512
#define BATCH   256
#define HID     1024
#define M1      (T_STEPS * BATCH)          // 131072 rows of X
#define OUT_FINAL ((size_t)T_STEPS * BATCH * HID)

typedef __attribute__((ext_vector_type(8))) short short8;     // 8 bf16 (4 VGPRs)
typedef __attribute__((ext_vector_type(4))) float floatx4;    // 4 fp32 acc
typedef __attribute__((ext_vector_type(8))) unsigned short ushort8;
typedef __attribute__((ext_vector_type(4))) unsigned short ushortx4;

static __device__ __forceinline__ unsigned short f32_to_bf16(float f) {
    unsigned int u = __float_as_uint(f);
    unsigned int r = (u + 0x7fffu + ((u >> 16) & 1u)) >> 16;   // RNE
    return (unsigned short)r;
}

// ---------------- converts ----------------
__global__ void k_convert(const float* __restrict__ w, unsigned short* __restrict__ o, int n) {
    int i = blockIdx.x * 256 + threadIdx.x;
    if (i < n) o[i] = f32_to_bf16(w[i]);
}

// Whh [k][n] fp32 -> WhhT [n][k] bf16 (coalesced reads along n)
__global__ void k_convert_T(const float* __restrict__ w, unsigned short* __restrict__ o) {
    int i = blockIdx.x * 256 + threadIdx.x;   // 0..1M
    int n = i & 1023, k = i >> 10;
    o[n * 1024 + k] = f32_to_bf16(w[k * 1024 + n]);
}

// ---------------- phase 1: xw GEMM ----------------
// C[M1][1024] = X(fp32->bf16) @ Wxh_bf16 + bh, 128x128 tile, 256 threads (2x2 waves of 64x64)
__global__ void __launch_bounds__(256) rnn_xw_gemm(const float* __restrict__ X,
                                                   const unsigned short* __restrict__ Wxh,
                                                   const float* __restrict__ bh,
                                                   float* __restrict__ out) {
    __shared__ unsigned short As[128 * 40];   // [row][k] stride 40 (pad: 2-way banks, free)
    __shared__ unsigned short Bs[128 * 40];   // [n][k]  stride 40

    const int tid  = threadIdx.x;
    const int lane = tid & 63;
    const int wave = tid >> 6;
    const int quad = lane >> 4;
    const int l15  = lane & 15;
    const int wr = wave >> 1, wc = wave & 1;

    const int bx = blockIdx.x;
    const int tile_n = bx & 7;          // 8 col tiles
    const int tile_m = bx >> 3;         // 1024 row tiles
    const int m0 = tile_m * 128;
    const int n0 = tile_n * 128;

    floatx4 acc[4][4];
#pragma unroll
    for (int i = 0; i < 4; ++i)
#pragma unroll
        for (int j = 0; j < 4; ++j) acc[i][j] = (floatx4){0.f, 0.f, 0.f, 0.f};

    for (int kt = 0; kt < 32; ++kt) {
        const int k0 = kt * 32;
        __syncthreads();
        // stage A: 128 rows x 32 k, fp32 -> bf16
#pragma unroll
        for (int it = 0; it < 4; ++it) {
            int i = tid + it * 256;                 // 0..1023
            int row = i >> 3, kq = (i & 7) * 4;
            const float4 v = *(const float4*)&X[(size_t)(m0 + row) * 1024 + k0 + kq];
            ushortx4 c;
            c.x = f32_to_bf16(v.x); c.y = f32_to_bf16(v.y);
            c.z = f32_to_bf16(v.z); c.w = f32_to_bf16(v.w);
            *(ushortx4*)&As[row * 40 + kq] = c;
        }
        // stage B transposed: Wxh[k0+k][n0 + n] -> Bs[n][k]
#pragma unroll
        for (int it = 0; it < 2; ++it) {
            int i = tid + it * 256;                 // 0..511
            int k = i >> 4, n8 = (i & 15) * 8;
            ushort8 wv = *(const ushort8*)&Wxh[(size_t)(k0 + k) * 1024 + n0 + n8];
#pragma unroll
            for (int j = 0; j < 8; ++j) Bs[(n8 + j) * 40 + k] = wv[j];
        }
        __syncthreads();

        short8 a[4], b[4];
#pragma unroll
        for (int i = 0; i < 4; ++i)
            a[i] = *(const short8*)&As[(wr * 64 + i * 16 + l15) * 40 + quad * 8];
#pragma unroll
        for (int j = 0; j < 4; ++j)
            b[j] = *(const short8*)&Bs[(wc * 64 + j * 16 + l15) * 40 + quad * 8];
#pragma unroll
        for (int i = 0; i < 4; ++i)
#pragma unroll
            for (int j = 0; j < 4; ++j)
                acc[i][j] = __builtin_amdgcn_mfma_f32_16x16x32_bf16(a[i], b[j], acc[i][j], 0, 0, 0);
    }

    // epilogue: D row = quad*4+r, col = l15 (verified m89 mapping)
#pragma unroll
    for (int j = 0; j < 4; ++j) {
        int col = n0 + wc * 64 + j * 16 + l15;
        float bhv = bh[col];
#pragma unroll
        for (int i = 0; i < 4; ++i) {
            int rowb = m0 + wr * 64 + i * 16 + quad * 4;
#pragma unroll
            for (int r = 0; r < 4; ++r)
                out[(size_t)(rowb + r) * 1024 + col] = acc[i][j][r] + bhv;
        }
    }
}

// ---------------- phase 2: recurrence ----------------
// grid = 256 blocks x 256 threads, LDS 129KB forces 1 block/CU (co-residency).
// team = blockIdx>>4 owns batch rows [team*16, +16); wg = blockIdx&15 owns cols [wid*64, +64).
__global__ void __launch_bounds__(256, 1) rnn_recurrent(float* __restrict__ out,
                                                        const unsigned short* __restrict__ WhhT,
                                                        unsigned short* __restrict__ sbuf,
                                                        unsigned int* __restrict__ bars) {
    extern __shared__ unsigned short Wt[];   // [64][1032]  (pad 8: 2-way banks, free)

    const int bx = blockIdx.x;
    const int team = bx >> 4;
    const int wid  = bx & 15;
    const int tid  = threadIdx.x;
    const int lane = tid & 63;
    const int wave = tid >> 6;
    const int quad = lane >> 4;
    const int l15  = lane & 15;
    const int r0 = team * 16;    // batch rows
    const int c0 = wid * 64;     // H cols

    // load W_hh^T slice: WhhT[c0+n][k] -> Wt[n][k]
    for (int i = tid; i < 64 * 128; i += 256) {
        int n = i >> 7, k8 = (i & 127) * 8;
        *(ushort8*)&Wt[n * 1032 + k8] = *(const ushort8*)&WhhT[(size_t)(c0 + n) * 1024 + k8];
    }
    __syncthreads();

    const int myn = wave * 16 + l15;          // this lane's column-in-slice (b_frag n = lane&15)
    const int h   = c0 + myn;                 // absolute H column of this lane's D outputs
    const unsigned short* wtq = &Wt[myn * 1032 + quad * 8];
    unsigned int* bar = &bars[team * 16];     // 64B-spaced counters

    for (int t = 0; t < T_STEPS; ++t) {
        const unsigned short* sr = sbuf + (size_t)(t & 1) * (BATCH * HID);
        unsigned short*       sw = sbuf + (size_t)((t + 1) & 1) * (BATCH * HID);

        // prefetch xw (phase-1 result lives in out[], overwritten below by tanh result)
        float xw[4];
#pragma unroll
        for (int r = 0; r < 4; ++r)
            xw[r] = out[(size_t)(t * BATCH + r0 + quad * 4 + r) * 1024 + h];

        // 16x16 tile: A = state rows [r0,r0+16) (A m = lane&15), B = Wt cols, K = 1024
        const unsigned short* sa = sr + (size_t)(r0 + l15) * 1024 + quad * 8;
        floatx4 acc0 = (floatx4){0.f, 0.f, 0.f, 0.f};
        floatx4 acc1 = (floatx4){0.f, 0.f, 0.f, 0.f};
#pragma unroll
        for (int k0 = 0; k0 < 1024; k0 += 64) {
            short8 a0 = *(const short8*)(sa + k0);
            short8 a1 = *(const short8*)(sa + k0 + 32);
            short8 b0 = *(const short8*)(wtq + k0);
            short8 b1 = *(const short8*)(wtq + k0 + 32);
            acc0 = __builtin_amdgcn_mfma_f32_16x16x32_bf16(a0, b0, acc0, 0, 0, 0);
            acc1 = __builtin_amdgcn_mfma_f32_16x16x32_bf16(a1, b1, acc1, 0, 0, 0);
        }
        floatx4 acc = acc0 + acc1;

#pragma unroll
        for (int r = 0; r < 4; ++r) {
            int row = r0 + quad * 4 + r;
            float v = tanhf(acc[r] + xw[r]);
            out[(size_t)(t * BATCH + row) * 1024 + h] = v;
            sw[(size_t)row * 1024 + h] = f32_to_bf16(v);
            if (t == T_STEPS - 1) out[OUT_FINAL + (size_t)row * 1024 + h] = v;
        }

        // per-team barrier (device scope; state crosses XCDs)
        __syncthreads();                       // wg stores drained (vmcnt(0) before s_barrier)
        if (tid == 0) {
            __threadfence();                   // release: flush to device scope
            atomicAdd(bar, 1u);
            const unsigned int tgt = 16u * (unsigned)(t + 1);
            while (__hip_atomic_load(bar, __ATOMIC_ACQUIRE, __HIP_MEMORY_SCOPE_AGENT) < tgt)
                __builtin_amdgcn_s_sleep(1);
        }
        __syncthreads();
    }
}

// ---------------- launch ----------------
extern "C" void kernel_launch(void* const* d_in, const int* in_sizes, int n_in,
                              void* d_out, int out_size, void* d_ws, size_t ws_size,
                              hipStream_t stream) {
    const float* X   = (const float*)d_in[0];   // [512,256,1024]
    const float* Wxh = (const float*)d_in[1];   // [1024,1024]
    const float* Whh = (const float*)d_in[2];   // [1024,1024]
    const float* bh  = (const float*)d_in[3];   // [1024]
    float* out = (float*)d_out;
    char* ws = (char*)d_ws;

    unsigned short* wxh_b = (unsigned short*)(ws);                    // 2 MB
    unsigned short* whh_t = (unsigned short*)(ws + (2u << 20));       // 2 MB
    unsigned short* sbuf  = (unsigned short*)(ws + (4u << 20));       // 1 MB (2x state bf16)
    unsigned int*   bars  = (unsigned int*)(ws + (5u << 20));         // 1 KB

    // zero state buffers (state0 = 0) + barrier counters (ws is poisoned 0xAA)
    hipMemsetAsync(ws + (4u << 20), 0, (1u << 20) + 1024, stream);

    k_convert  <<<4096, 256, 0, stream>>>(Wxh, wxh_b, 1024 * 1024);
    k_convert_T<<<4096, 256, 0, stream>>>(Whh, whh_t);

    rnn_xw_gemm<<<8192, 256, 0, stream>>>(X, wxh_b, bh, out);

    (void)hipFuncSetAttribute((const void*)rnn_recurrent,
                              hipFuncAttributeMaxDynamicSharedMemorySize, 64 * 1032 * 2);
    rnn_recurrent<<<256, 256, 64 * 1032 * 2, stream>>>(out, whh_t, sbuf, bars);
}